// Round 5
// baseline (560.414 us; speedup 1.0000x reference)
//
#include <hip/hip_runtime.h>
#include <hip/hip_bf16.h>
#include <cmath>

typedef __attribute__((ext_vector_type(4))) float f32x4;
typedef __attribute__((ext_vector_type(8))) short s16x8;

typedef __attribute__((address_space(1))) const void glb_void_t;
typedef __attribute__((address_space(3))) void lds_void_t;

#define MFMA(a, b, c) __builtin_amdgcn_mfma_f32_16x16x32_bf16(a, b, c, 0, 0, 0)
#define GLOAD_LDS(g, l) __builtin_amdgcn_global_load_lds((glb_void_t*)(g), (lds_void_t*)(l), 16, 0, 0)

__device__ __forceinline__ unsigned short bf(float x) {
  union { float f; unsigned u; } c; c.f = x;
  unsigned r = (c.u + 0x7fffu + ((c.u >> 16) & 1u)) >> 16;
  return (unsigned short)r;
}

// ---------------- kernel 0: weight prep (f32 -> bf16, stacked) ----------------
__global__ void k_prep(const float* __restrict__ wq, const float* __restrict__ wk,
                       const float* __restrict__ wv, const float* __restrict__ bq,
                       const float* __restrict__ bk, const float* __restrict__ bv,
                       const float* __restrict__ wo,
                       __hip_bfloat16* __restrict__ wqkv, __hip_bfloat16* __restrict__ wob,
                       float* __restrict__ bqkv) {
  const int NW = 1536 * 1024, NO = 1024 * 512;
  for (int i = blockIdx.x * blockDim.x + threadIdx.x; i < NW + NO + 1536;
       i += gridDim.x * blockDim.x) {
    if (i < NW) {
      int r = i >> 10;
      float v = (r < 512) ? wq[i] : ((r < 1024) ? wk[i - 512 * 1024] : wv[i - 1024 * 1024]);
      ((unsigned short*)wqkv)[i] = bf(v);
    } else if (i < NW + NO) {
      int j = i - NW;
      ((unsigned short*)wob)[j] = bf(wo[j]);
    } else {
      int j = i - NW - NO;
      bqkv[j] = (j < 512) ? bq[j] : ((j < 1024) ? bk[j - 512] : bv[j - 1024]);
    }
  }
}

// ---------------- kernel 0b: qk [b][d][t] f32 -> qkT [b][t][d] bf16 ----------------
__global__ __launch_bounds__(256) void k_transpose(const float* __restrict__ qk,
                                                   __hip_bfloat16* __restrict__ qkT) {
  __shared__ float tile[64][65];
  const int b = blockIdx.z, t0 = blockIdx.x * 64, d0 = blockIdx.y * 64;
  const int tid = threadIdx.x;
  const int tq = tid & 15, dr = tid >> 4;
  const float* src = qk + ((size_t)b * 1024 + d0) * 8192 + t0;
#pragma unroll
  for (int i = 0; i < 4; i++) {
    int d = dr + i * 16;
    float4 v = *(const float4*)(src + (size_t)d * 8192 + tq * 4);
    tile[d][tq * 4 + 0] = v.x; tile[d][tq * 4 + 1] = v.y;
    tile[d][tq * 4 + 2] = v.z; tile[d][tq * 4 + 3] = v.w;
  }
  __syncthreads();
  const int d4 = (tid & 15) * 4, tr = tid >> 4;
  unsigned short* dst = (unsigned short*)qkT + ((size_t)b * 8192 + t0) * 1024 + d0;
#pragma unroll
  for (int i = 0; i < 4; i++) {
    int t = tr + i * 16;
    ushort4 o4;
    o4.x = bf(tile[d4 + 0][t]); o4.y = bf(tile[d4 + 1][t]);
    o4.z = bf(tile[d4 + 2][t]); o4.w = bf(tile[d4 + 3][t]);
    *(ushort4*)(dst + (size_t)t * 1024 + d4) = o4;
  }
}

// stage one 128x64(bf16) half-tile: 8 waves x 2 rounds, LDS linear, source pre-swizzled
__device__ __forceinline__ void stage_half(char* lds_base, const char* gbase,
                                           int ktile, int w, int l) {
#pragma unroll
  for (int r = 0; r < 2; ++r) {
    int row = r * 64 + w * 8 + (l >> 3);
    int cb = ((l & 7) * 16) ^ ((row & 7) << 4);
    GLOAD_LDS(gbase + (size_t)row * 2048 + (size_t)ktile * 128 + cb,
              lds_base + (r * 64 + w * 8) * 128);
  }
}

// ---------------- kernel A: qkv[b][t][o] = qkT[b]·wqkv^T + bias (bf16) ----------------
// 256x256 tile, BK=64, 8 waves (2M x 4N), wave output 128x64.
// A staged in LDS (dbuf, 64KB). B (weights, 3MB, L2-hot) read DIRECTLY from
// global into registers (64B-sector coalesced), halving LDS read traffic:
// LDS/K-tile ~1900cyc < MFMA 2065cyc -> MFMA-bound. 2 barriers per K-tile.
__global__ __launch_bounds__(512) void k_qkv(const __hip_bfloat16* __restrict__ qkT,
                                             const __hip_bfloat16* __restrict__ wqkv,
                                             const float* __restrict__ bqkv,
                                             __hip_bfloat16* __restrict__ qkv) {
  __shared__ char smem[65536];   // A only: [buf][half] 2buf x 2half x 128rows x 128B
  const int NT = 16;             // K=1024 / BK=64
  const int b = blockIdx.z, t0 = blockIdx.x * 256, o0 = blockIdx.y * 256;
  const int tid = threadIdx.x, l = tid & 63, w = tid >> 6;
  const int c = l & 15, g = l >> 4;
  const int wm = w >> 2, wn = w & 3;
  const int cbase = (g * 16) ^ ((c & 7) << 4);  // ds_read col-byte for kk=0

  const char* qpanel = (const char*)qkT + ((size_t)b * 8192 + t0) * 2048;
  const char* wpanel = (const char*)wqkv + (size_t)o0 * 2048;
  // per-lane B row base (o-row = o0 + wn*64 + ni*16 + c)
  const char* brow_base = wpanel + (size_t)(wn * 64 + c) * 2048 + g * 16;

#define STAGE_A(tt) { stage_half(smem + ((tt)&1) * 32768, qpanel, (tt), w, l); \
                      stage_half(smem + ((tt)&1) * 32768 + 16384, qpanel + 262144, (tt), w, l); }
#define BFRAG(tt, ni, kk) (*(const s16x8*)(brow_base + (size_t)(ni) * (16 * 2048) + (size_t)(tt) * 128 + (kk) * 64))

  f32x4 acc[8][4];
#pragma unroll
  for (int i = 0; i < 8; i++)
#pragma unroll
    for (int j = 0; j < 4; j++) acc[i][j] = (f32x4){0.f, 0.f, 0.f, 0.f};

  // B fragments live in regs; reloaded in-place right after last use each tile.
  s16x8 bvLo[2][2], bvHi[2][2];
#pragma unroll
  for (int ni = 0; ni < 2; ++ni)
#pragma unroll
    for (int kk = 0; kk < 2; ++kk) {
      bvLo[ni][kk] = BFRAG(0, ni, kk);
      bvHi[ni][kk] = BFRAG(0, 2 + ni, kk);
    }
  __builtin_amdgcn_sched_barrier(0);
  // prologue staging: tiles 0 and 1 (8 gload_lds per wave after the B loads)
  STAGE_A(0); STAGE_A(1);
  asm volatile("s_waitcnt vmcnt(4)" ::: "memory");  // A(0) landed (A(1)'s 4 may remain)
  __builtin_amdgcn_s_barrier();

#pragma unroll 2
  for (int t = 0; t < NT; ++t) {
    const char* Ah = smem + (t & 1) * 32768 + wm * 16384;

    // fragment reads for CURRENT tile; avLo first so Q00's operand wait is minimal
    s16x8 avLo[4][2], avHi[4][2];
#pragma unroll
    for (int mi = 0; mi < 4; ++mi)
#pragma unroll
      for (int kk = 0; kk < 2; ++kk)
        avLo[mi][kk] = *(const s16x8*)(Ah + (mi * 16 + c) * 128 + (cbase ^ (kk << 6)));
    __builtin_amdgcn_sched_barrier(0);
#pragma unroll
    for (int mi = 0; mi < 4; ++mi)
#pragma unroll
      for (int kk = 0; kk < 2; ++kk)
        avHi[mi][kk] = *(const s16x8*)(Ah + (64 + mi * 16 + c) * 128 + (cbase ^ (kk << 6)));

    // Q00 + Q01 + Q10 (48 MFMA) — LDS reads stream underneath (compiler lgkm)
    __builtin_amdgcn_s_setprio(1);
#pragma unroll
    for (int mi = 0; mi < 4; ++mi)
#pragma unroll
      for (int ni = 0; ni < 2; ++ni)
#pragma unroll
        for (int kk = 0; kk < 2; ++kk)
          acc[mi][ni] = MFMA(avLo[mi][kk], bvLo[ni][kk], acc[mi][ni]);
#pragma unroll
    for (int mi = 0; mi < 4; ++mi)
#pragma unroll
      for (int ni = 0; ni < 2; ++ni)
#pragma unroll
        for (int kk = 0; kk < 2; ++kk)
          acc[mi][ni + 2] = MFMA(avLo[mi][kk], bvHi[ni][kk], acc[mi][ni + 2]);
#pragma unroll
    for (int mi = 0; mi < 4; ++mi)
#pragma unroll
      for (int ni = 0; ni < 2; ++ni)
#pragma unroll
        for (int kk = 0; kk < 2; ++kk)
          acc[mi + 4][ni] = MFMA(avHi[mi][kk], bvLo[ni][kk], acc[mi + 4][ni]);
    __builtin_amdgcn_s_setprio(0);

    // bvLo dead -> reload for t+1 (uses Q11+barriers+next-Q00 gap to land)
    if (t + 1 < NT) {
#pragma unroll
      for (int ni = 0; ni < 2; ++ni)
#pragma unroll
        for (int kk = 0; kk < 2; ++kk)
          bvLo[ni][kk] = BFRAG(t + 1, ni, kk);
    }

    // B2: all waves' ds_reads of buf[t] are done (operand waits before Q10).
    __builtin_amdgcn_s_barrier();
    if (t + 2 < NT) STAGE_A(t + 2);

    __builtin_amdgcn_s_setprio(1);
#pragma unroll
    for (int mi = 0; mi < 4; ++mi)
#pragma unroll
      for (int ni = 0; ni < 2; ++ni)
#pragma unroll
        for (int kk = 0; kk < 2; ++kk)
          acc[mi + 4][ni + 2] = MFMA(avHi[mi][kk], bvHi[ni][kk], acc[mi + 4][ni + 2]);
    __builtin_amdgcn_s_setprio(0);

    if (t + 1 < NT) {
#pragma unroll
      for (int ni = 0; ni < 2; ++ni)
#pragma unroll
        for (int kk = 0; kk < 2; ++kk)
          bvHi[ni][kk] = BFRAG(t + 1, 2 + ni, kk);
    }

    // B1: certify A(t+1) landed for all waves, then next tile reads it.
    // Set-based vmcnt: ops issued after stage A(t+1) = 16 steady (12 at t=0
    // and t=NT-2, where one stage/B-load group is absent).
    if (t < NT - 1) {
      if (t == 0 || t + 2 >= NT) {
        asm volatile("s_waitcnt vmcnt(12)" ::: "memory");
      } else {
        asm volatile("s_waitcnt vmcnt(16)" ::: "memory");
      }
      __builtin_amdgcn_s_barrier();
    }
  }
#undef STAGE_A
#undef BFRAG

  // epilogue: + bias, -> bf16, qkv[b][t][o]
  unsigned short* outb = (unsigned short*)qkv + ((size_t)b * 8192 + t0) * 1536 + o0;
  float bias[4];
#pragma unroll
  for (int ni = 0; ni < 4; ni++) bias[ni] = bqkv[o0 + wn * 64 + ni * 16 + c];
#pragma unroll
  for (int mi = 0; mi < 8; mi++)
#pragma unroll
    for (int r = 0; r < 4; r++) {
      int t = wm * 128 + mi * 16 + g * 4 + r;
#pragma unroll
      for (int ni = 0; ni < 4; ni++) {
        int o = wn * 64 + ni * 16 + c;
        outb[(size_t)t * 1536 + o] = bf(acc[mi][ni][r] + bias[ni]);
      }
    }
}

// ---------------- kernel B: attention per (bg, h), 1 wave ----------------
__global__ __launch_bounds__(64) void k_attn(const __hip_bfloat16* __restrict__ qkv,
                                             const float* __restrict__ masks,
                                             __hip_bfloat16* __restrict__ a_out) {
  const int l = threadIdx.x, c = l & 15, g = l >> 4;
  const int h = blockIdx.x & 7, bg = blockIdx.x >> 3;
  const int gg = bg & 127, b = bg >> 7;
  const size_t rowstep = (size_t)128 * 1536;  // t += 128
  const __hip_bfloat16* base = qkv + ((size_t)b * 8192 + gg) * 1536 + h * 64;
  const __hip_bfloat16* Qb = base;
  const __hip_bfloat16* Kb = base + 512;
  const __hip_bfloat16* Vb = base + 1024;

  // load Q,K fragments (Q[i][d], K[j][d]; d k-contiguous)
  s16x8 kf[4][2], qf[4][2];
#pragma unroll
  for (int f = 0; f < 4; f++)
#pragma unroll
    for (int kk = 0; kk < 2; kk++) {
      size_t roff = (size_t)(f * 16 + c) * rowstep + kk * 32 + g * 8;
      kf[f][kk] = *(const s16x8*)(Kb + roff);
      qf[f][kk] = *(const s16x8*)(Qb + roff);
    }
  // S^T = K · Q^T : st[mj][ni], row=j, col=i
  f32x4 st[4][4];
#pragma unroll
  for (int i = 0; i < 4; i++)
#pragma unroll
    for (int j = 0; j < 4; j++) st[i][j] = (f32x4){0.f, 0.f, 0.f, 0.f};
#pragma unroll
  for (int mj = 0; mj < 4; mj++)
#pragma unroll
    for (int ni = 0; ni < 4; ni++)
#pragma unroll
      for (int kk = 0; kk < 2; kk++)
        st[mj][ni] = MFMA(kf[mj][kk], qf[ni][kk], st[mj][ni]);

  // key-side mask values for this lane's j rows
  float mk[4][4];
#pragma unroll
  for (int mj = 0; mj < 4; mj++)
#pragma unroll
    for (int r = 0; r < 4; r++)
      mk[mj][r] = masks[(size_t)b * 8192 + (size_t)(mj * 16 + g * 4 + r) * 128 + gg];

  // scale + mask + column softmax (over j)
  float inv[4];
#pragma unroll
  for (int ni = 0; ni < 4; ni++) {
    float m = -1e30f;
#pragma unroll
    for (int mj = 0; mj < 4; mj++)
#pragma unroll
      for (int r = 0; r < 4; r++) {
        float s = st[mj][ni][r] * 0.125f;
        s = (mk[mj][r] > 0.f) ? s : -1e9f;
        st[mj][ni][r] = s;
        m = fmaxf(m, s);
      }
    m = fmaxf(m, __shfl_xor(m, 16));
    m = fmaxf(m, __shfl_xor(m, 32));
    float sm = 0.f;
#pragma unroll
    for (int mj = 0; mj < 4; mj++)
#pragma unroll
      for (int r = 0; r < 4; r++) {
        float p = expf(st[mj][ni][r] - m);
        st[mj][ni][r] = p;
        sm += p;
      }
    sm += __shfl_xor(sm, 16);
    sm += __shfl_xor(sm, 32);
    inv[ni] = 1.f / sm;
  }
#pragma unroll
  for (int mj = 0; mj < 4; mj++)
#pragma unroll
    for (int ni = 0; ni < 4; ni++)
#pragma unroll
      for (int r = 0; r < 4; r++) st[mj][ni][r] *= inv[ni];

  // pack P^T to bf16 dwords: qd[ni][mj][w] = {reg 2w, reg 2w+1}
  unsigned qd[4][4][2];
#pragma unroll
  for (int ni = 0; ni < 4; ni++)
#pragma unroll
    for (int mj = 0; mj < 4; mj++)
#pragma unroll
      for (int wv = 0; wv < 2; wv++)
        qd[ni][mj][wv] = (unsigned)bf(st[mj][ni][2 * wv]) |
                         ((unsigned)bf(st[mj][ni][2 * wv + 1]) << 16);

  // PV: O[i][dh] += P[i][j] V[j][dh]
  f32x4 oacc[4][4];
#pragma unroll
  for (int i = 0; i < 4; i++)
#pragma unroll
    for (int j = 0; j < 4; j++) oacc[i][j] = (f32x4){0.f, 0.f, 0.f, 0.f};

  const int srcA = c + 32 * (g & 1);
  const int srcB = srcA + 16;
  const bool hi = (g >= 2);
#pragma unroll
  for (int kk = 0; kk < 2; kk++) {
    s16x8 af[4];
#pragma unroll
    for (int ni = 0; ni < 4; ni++) {
      unsigned a0 = __shfl(qd[ni][2 * kk][0], srcA);
      unsigned b0 = __shfl(qd[ni][2 * kk + 1][0], srcA);
      unsigned a1 = __shfl(qd[ni][2 * kk][1], srcA);
      unsigned b1 = __shfl(qd[ni][2 * kk + 1][1], srcA);
      unsigned a2 = __shfl(qd[ni][2 * kk][0], srcB);
      unsigned b2 = __shfl(qd[ni][2 * kk + 1][0], srcB);
      unsigned a3 = __shfl(qd[ni][2 * kk][1], srcB);
      unsigned b3 = __shfl(qd[ni][2 * kk + 1][1], srcB);
      union { unsigned u[4]; s16x8 v; } uu;
      uu.u[0] = hi ? b0 : a0;
      uu.u[1] = hi ? b1 : a1;
      uu.u[2] = hi ? b2 : a2;
      uu.u[3] = hi ? b3 : a3;
      af[ni] = uu.v;
    }
    s16x8 bvv[4];
#pragma unroll
    for (int fd = 0; fd < 4; fd++) {
      s16x8 t;
#pragma unroll
      for (int e = 0; e < 8; e++)
        t[e] = *(const short*)(Vb + (size_t)(kk * 32 + g * 8 + e) * rowstep + fd * 16 + c);
      bvv[fd] = t;
    }
#pragma unroll
    for (int fi = 0; fi < 4; fi++)
#pragma unroll
      for (int fd = 0; fd < 4; fd++)
        oacc[fi][fd] = MFMA(af[fi], bvv[fd], oacc[fi][fd]);
  }

  // GELU + store a[b][t][dk]
  unsigned short* ob = (unsigned short*)a_out + ((size_t)b * 8192 + gg) * 512 + h * 64;
#pragma unroll
  for (int fi = 0; fi < 4; fi++)
#pragma unroll
    for (int fd = 0; fd < 4; fd++)
#pragma unroll
      for (int r = 0; r < 4; r++) {
        float x = oacc[fi][fd][r];
        float ge = 0.5f * x * (1.f + erff(x * 0.70710678118f));
        int i = fi * 16 + g * 4 + r;
        ob[(size_t)i * (128 * 512) + fd * 16 + c] = bf(ge);
      }
}

// ---------------- kernel C: y[b][od][t] = (wo·a^T + bo) * mask (f32) ----------------
// M=od (256/WG), N=t (128/WG), K=512. 8 waves (4m x 2n).
__global__ __launch_bounds__(512) void k_out(const __hip_bfloat16* __restrict__ wob,
                                             const __hip_bfloat16* __restrict__ a,
                                             const float* __restrict__ bo,
                                             const float* __restrict__ masks,
                                             float* __restrict__ y) {
  __shared__ char smem[256 * 128 + 128 * 128];
  char* As = smem;            // 256 rows(od) x 128B
  char* Bs = smem + 32768;    // 128 rows(t) x 128B
  const int b = blockIdx.z, t0 = blockIdx.x * 128, o0 = blockIdx.y * 256;
  const int tid = threadIdx.x, l = tid & 63, w = tid >> 6;
  const int c = l & 15, g = l >> 4;
  const int wm = w >> 1, wn = w & 1;
  const int lrow = l >> 3, lcol = (l & 7) * 16;

  f32x4 acc[4][4];
#pragma unroll
  for (int i = 0; i < 4; i++)
#pragma unroll
    for (int j = 0; j < 4; j++) acc[i][j] = (f32x4){0.f, 0.f, 0.f, 0.f};

  const char* wbase = (const char*)(wob + (size_t)o0 * 512);
  const char* abase = (const char*)(a + ((size_t)b * 8192 + t0) * 512);

  for (int ks = 0; ks < 8; ks++) {
    __syncthreads();
#pragma unroll
    for (int ii = 0; ii < 4; ii++) {
      int row = w * 32 + ii * 8 + lrow;
      int cb = lcol ^ ((row & 7) << 4);
      const char* gp = wbase + (size_t)row * 1024 + ks * 128 + cb;
      GLOAD_LDS(gp, As + (w * 32 + ii * 8) * 128);
    }
#pragma unroll
    for (int ii = 0; ii < 2; ii++) {
      int row = w * 16 + ii * 8 + lrow;
      int cb = lcol ^ ((row & 7) << 4);
      const char* gp = abase + (size_t)row * 1024 + ks * 128 + cb;
      GLOAD_LDS(gp, Bs + (w * 16 + ii * 8) * 128);
    }
    __syncthreads();
#pragma unroll
    for (int kk = 0; kk < 2; kk++) {
      s16x8 av[4], bv[4];
#pragma unroll
      for (int mi = 0; mi < 4; mi++) {
        int row = wm * 64 + mi * 16 + c;
        int cb = (kk * 64 + g * 16) ^ ((row & 7) << 4);
        av[mi] = *(const s16x8*)(As + row * 128 + cb);
      }
#pragma unroll
      for (int ni = 0; ni < 4; ni++) {
        int row = wn * 64 + ni * 16 + c;
        int cb = (kk * 64 + g * 16) ^ ((row & 7) << 4);
        bv[ni] = *(const s16x8*)(Bs + row * 128 + cb);
      }
#pragma unroll
      for (int mi = 0; mi < 4; mi++)
#pragma unroll
        for (int ni = 0; ni < 4; ni++)
          acc[mi][ni] = MFMA(av[mi], bv[ni], acc[mi][ni]);
    }
  }
  // epilogue
  int tcol[4];
  float mk[4];
#pragma unroll
  for (int ni = 0; ni < 4; ni++) {
    tcol[ni] = t0 + wn * 64 + ni * 16 + c;
    mk[ni] = masks[(size_t)b * 8192 + tcol[ni]];
  }
#pragma unroll
  for (int mi = 0; mi < 4; mi++)
#pragma unroll
    for (int r = 0; r < 4; r++) {
      int od = o0 + wm * 64 + mi * 16 + g * 4 + r;
      float bias = bo[od];
      float* yrow = y + ((size_t)b * 1024 + od) * 8192;
#pragma unroll
      for (int ni = 0; ni < 4; ni++)
        yrow[tcol[ni]] = (acc[mi][ni][r] + bias) * mk[ni];
    }
}

// ---------------- launch ----------------
extern "C" void kernel_launch(void* const* d_in, const int* in_sizes, int n_in,
                              void* d_out, int out_size, void* d_ws, size_t ws_size,
                              hipStream_t stream) {
  const float* qk = (const float*)d_in[0];
  const float* masks = (const float*)d_in[1];
  const float* wq = (const float*)d_in[2];
  const float* bq = (const float*)d_in[3];
  const float* wk = (const float*)d_in[4];
  const float* bk = (const float*)d_in[5];
  const float* wv = (const float*)d_in[6];
  const float* bv = (const float*)d_in[7];
  const float* wo = (const float*)d_in[8];
  const float* bo = (const float*)d_in[9];

  char* ws = (char*)d_ws;
  __hip_bfloat16* qkT = (__hip_bfloat16*)ws;                       // 128 MB, dead after k_qkv
  __hip_bfloat16* a = (__hip_bfloat16*)ws;                         // 64 MB, written after qkT dead
  __hip_bfloat16* wqkv = (__hip_bfloat16*)(ws + 134217728);        // 3 MB
  __hip_bfloat16* wob = (__hip_bfloat16*)(ws + 134217728 + 3145728);  // 1 MB
  float* bqkv = (float*)(ws + 134217728 + 3145728 + 1048576);      // 6 KB

  __hip_bfloat16* qkv = (__hip_bfloat16*)d_out;  // 192 MB scratch in d_out (f32 out = 256 MB)
  float* y = (float*)d_out;

  k_prep<<<dim3(512), dim3(256), 0, stream>>>(wq, wk, wv, bq, bk, bv, wo, wqkv, wob, bqkv);
  k_transpose<<<dim3(128, 16, 8), dim3(256), 0, stream>>>(qk, qkT);
  k_qkv<<<dim3(32, 6, 8), dim3(512), 0, stream>>>(qkT, wqkv, bqkv, qkv);
  k_attn<<<dim3(8192), dim3(64), 0, stream>>>(qkv, masks, a);
  k_out<<<dim3(64, 4, 8), dim3(512), 0, stream>>>(wob, a, bo, masks, y);
}

// Round 6
// 465.990 us; speedup vs baseline: 1.2026x; 1.2026x over previous
//
#include <hip/hip_runtime.h>
#include <hip/hip_bf16.h>
#include <cmath>

typedef __attribute__((ext_vector_type(4))) float f32x4;
typedef __attribute__((ext_vector_type(8))) short s16x8;

typedef __attribute__((address_space(1))) const void glb_void_t;
typedef __attribute__((address_space(3))) void lds_void_t;

#define MFMA(a, b, c) __builtin_amdgcn_mfma_f32_16x16x32_bf16(a, b, c, 0, 0, 0)
#define GLOAD_LDS(g, l) __builtin_amdgcn_global_load_lds((glb_void_t*)(g), (lds_void_t*)(l), 16, 0, 0)

__device__ __forceinline__ unsigned short bf(float x) {
  union { float f; unsigned u; } c; c.f = x;
  unsigned r = (c.u + 0x7fffu + ((c.u >> 16) & 1u)) >> 16;
  return (unsigned short)r;
}

// ---------------- kernel 0: weight prep (f32 -> bf16, stacked) ----------------
__global__ void k_prep(const float* __restrict__ wq, const float* __restrict__ wk,
                       const float* __restrict__ wv, const float* __restrict__ bq,
                       const float* __restrict__ bk, const float* __restrict__ bv,
                       const float* __restrict__ wo,
                       __hip_bfloat16* __restrict__ wqkv, __hip_bfloat16* __restrict__ wob,
                       float* __restrict__ bqkv) {
  const int NW = 1536 * 1024, NO = 1024 * 512;
  for (int i = blockIdx.x * blockDim.x + threadIdx.x; i < NW + NO + 1536;
       i += gridDim.x * blockDim.x) {
    if (i < NW) {
      int r = i >> 10;
      float v = (r < 512) ? wq[i] : ((r < 1024) ? wk[i - 512 * 1024] : wv[i - 1024 * 1024]);
      ((unsigned short*)wqkv)[i] = bf(v);
    } else if (i < NW + NO) {
      int j = i - NW;
      ((unsigned short*)wob)[j] = bf(wo[j]);
    } else {
      int j = i - NW - NO;
      bqkv[j] = (j < 512) ? bq[j] : ((j < 1024) ? bk[j - 512] : bv[j - 1024]);
    }
  }
}

// ---------------- kernel 0b: qk [b][d][t] f32 -> qkT [b][t][d] bf16 ----------------
__global__ __launch_bounds__(256) void k_transpose(const float* __restrict__ qk,
                                                   __hip_bfloat16* __restrict__ qkT) {
  __shared__ float tile[64][65];
  const int b = blockIdx.z, t0 = blockIdx.x * 64, d0 = blockIdx.y * 64;
  const int tid = threadIdx.x;
  const int tq = tid & 15, dr = tid >> 4;
  const float* src = qk + ((size_t)b * 1024 + d0) * 8192 + t0;
#pragma unroll
  for (int i = 0; i < 4; i++) {
    int d = dr + i * 16;
    float4 v = *(const float4*)(src + (size_t)d * 8192 + tq * 4);
    tile[d][tq * 4 + 0] = v.x; tile[d][tq * 4 + 1] = v.y;
    tile[d][tq * 4 + 2] = v.z; tile[d][tq * 4 + 3] = v.w;
  }
  __syncthreads();
  const int d4 = (tid & 15) * 4, tr = tid >> 4;
  unsigned short* dst = (unsigned short*)qkT + ((size_t)b * 8192 + t0) * 1024 + d0;
#pragma unroll
  for (int i = 0; i < 4; i++) {
    int t = tr + i * 16;
    ushort4 o4;
    o4.x = bf(tile[d4 + 0][t]); o4.y = bf(tile[d4 + 1][t]);
    o4.z = bf(tile[d4 + 2][t]); o4.w = bf(tile[d4 + 3][t]);
    *(ushort4*)(dst + (size_t)t * 1024 + d4) = o4;
  }
}

// stage one 128x64(bf16) half-tile: 8 waves x 2 rounds, LDS linear, source pre-swizzled
__device__ __forceinline__ void stage_half(char* lds_base, const char* gbase,
                                           int ktile, int w, int l) {
#pragma unroll
  for (int r = 0; r < 2; ++r) {
    int row = r * 64 + w * 8 + (l >> 3);
    int cb = ((l & 7) * 16) ^ ((row & 7) << 4);
    GLOAD_LDS(gbase + (size_t)row * 2048 + (size_t)ktile * 128 + cb,
              lds_base + (r * 64 + w * 8) * 128);
  }
}

// ---------------- kernel A: qkv[b][t][o] = qkT[b]·wqkv^T + bias (bf16) ----------------
// m201-faithful 8-phase 256x256, BK=64, 8 waves (2M x 4N), wave tile 128x64.
// Per K-tile, 4 phases: {reads for THIS phase's MFMA | stage one half-tile |
// [lgkm(8)] | barrier | lgkm(0) | 16 MFMA | barrier}. Even read spread
// 12/4/8/0. Stage slots: PH1=A0(t+1), PH2=A1(t+1), PH3=B0(t+2), PH4=B1(t+2);
// single counted vmcnt(4) at PH4 certifies exactly tile t+1 (op-ledger
// verified); tail t>=NT-2 uses vmcnt(0).
__global__ __launch_bounds__(512) void k_qkv(const __hip_bfloat16* __restrict__ qkT,
                                             const __hip_bfloat16* __restrict__ wqkv,
                                             const float* __restrict__ bqkv,
                                             __hip_bfloat16* __restrict__ qkv) {
  __shared__ char smem[131072];  // A: [par][half] 4x16KB at 0; B: same at 65536
  const int NT = 16;             // K=1024 / BK=64
  const int b = blockIdx.z, t0 = blockIdx.x * 256, o0 = blockIdx.y * 256;
  const int tid = threadIdx.x, l = tid & 63, w = tid >> 6;
  const int c = l & 15, g = l >> 4;
  const int wm = w >> 2, wn = w & 3;
  const int cbase = (g * 16) ^ ((c & 7) << 4);  // ds_read col-byte for kk=0
  const int brow = (wn & 1) * 64;

  const char* qpanel = (const char*)qkT + ((size_t)b * 8192 + t0) * 2048;
  const char* wpanel = (const char*)wqkv + (size_t)o0 * 2048;

#define STG_A(PAR, h, tt) stage_half(smem + (PAR) * 32768 + (h) * 16384, \
                                     qpanel + (size_t)(h) * 262144, (tt), w, l)
#define STG_B(PAR, h, tt) stage_half(smem + 65536 + (PAR) * 32768 + (h) * 16384, \
                                     wpanel + (size_t)(h) * 262144, (tt), w, l)
#define RD(base, row, kk) (*(const s16x8*)((base) + (row) * 128 + (cbase ^ ((kk) << 6))))

  f32x4 acc[8][4];
#pragma unroll
  for (int i = 0; i < 8; i++)
#pragma unroll
    for (int j = 0; j < 4; j++) acc[i][j] = (f32x4){0.f, 0.f, 0.f, 0.f};

  // prologue ledger: A(0)4 + B(0)4 + B(1)4 = 12 ops; vmcnt(4) leaves B(1).
  STG_A(0, 0, 0); STG_A(0, 1, 0); STG_B(0, 0, 0); STG_B(0, 1, 0);
  STG_B(1, 0, 1); STG_B(1, 1, 1);
  asm volatile("s_waitcnt vmcnt(4)" ::: "memory");
  __builtin_amdgcn_s_barrier();

#define QUAD(AV, BV, AOFF, NOFF)                                          \
  _Pragma("unroll") for (int mi = 0; mi < 4; ++mi)                        \
  _Pragma("unroll") for (int ni = 0; ni < 2; ++ni)                        \
  _Pragma("unroll") for (int kk = 0; kk < 2; ++kk)                        \
    acc[mi + AOFF][ni + NOFF] = MFMA(AV[mi][kk], BV[ni][kk], acc[mi + AOFF][ni + NOFF]);

  for (int t = 0; t < NT; ++t) {
    const int PAR = t & 1;
    const char* Ab = smem + PAR * 32768 + wm * 16384;            // wave's A half
    const char* Bb = smem + 65536 + PAR * 32768 + (wn >> 1) * 16384;
    const bool doA = (t + 1 < NT);
    const bool doB = (t + 2 < NT);
    s16x8 avLo[4][2], avHi[4][2], bvLo[2][2], bvHi[2][2];

    // ---- PH1: read avLo(8)+bvLo(4); stage A0(t+1); Q1 = lo x lo ----
#pragma unroll
    for (int mi = 0; mi < 4; ++mi)
#pragma unroll
      for (int kk = 0; kk < 2; ++kk)
        avLo[mi][kk] = RD(Ab, mi * 16 + c, kk);
#pragma unroll
    for (int ni = 0; ni < 2; ++ni)
#pragma unroll
      for (int kk = 0; kk < 2; ++kk)
        bvLo[ni][kk] = RD(Bb, brow + ni * 16 + c, kk);
    if (doA) STG_A(PAR ^ 1, 0, t + 1);
    asm volatile("s_waitcnt lgkmcnt(8)" ::: "memory");
    __builtin_amdgcn_s_barrier();
    asm volatile("s_waitcnt lgkmcnt(0)" ::: "memory");
    __builtin_amdgcn_sched_barrier(0);
    __builtin_amdgcn_s_setprio(1);
    QUAD(avLo, bvLo, 0, 0);
    __builtin_amdgcn_s_setprio(0);
    __builtin_amdgcn_s_barrier();

    // ---- PH2: read bvHi(4); stage A1(t+1); Q2 = lo x hi ----
#pragma unroll
    for (int ni = 0; ni < 2; ++ni)
#pragma unroll
      for (int kk = 0; kk < 2; ++kk)
        bvHi[ni][kk] = RD(Bb, brow + 32 + ni * 16 + c, kk);
    if (doA) STG_A(PAR ^ 1, 1, t + 1);
    __builtin_amdgcn_s_barrier();
    asm volatile("s_waitcnt lgkmcnt(0)" ::: "memory");
    __builtin_amdgcn_sched_barrier(0);
    __builtin_amdgcn_s_setprio(1);
    QUAD(avLo, bvHi, 0, 2);
    __builtin_amdgcn_s_setprio(0);
    __builtin_amdgcn_s_barrier();

    // ---- PH3: read avHi(8); stage B0(t+2) [B(t) reads done by PH2-end]; Q3 ----
#pragma unroll
    for (int mi = 0; mi < 4; ++mi)
#pragma unroll
      for (int kk = 0; kk < 2; ++kk)
        avHi[mi][kk] = RD(Ab, 64 + mi * 16 + c, kk);
    if (doB) STG_B(PAR, 0, t + 2);
    __builtin_amdgcn_s_barrier();
    asm volatile("s_waitcnt lgkmcnt(0)" ::: "memory");
    __builtin_amdgcn_sched_barrier(0);
    __builtin_amdgcn_s_setprio(1);
    QUAD(avHi, bvLo, 4, 0);
    __builtin_amdgcn_s_setprio(0);
    __builtin_amdgcn_s_barrier();

    // ---- PH4: stage B1(t+2); vmcnt(4) certifies tile t+1; Q4 ----
    if (doB) STG_B(PAR, 1, t + 2);
    if (t < NT - 2) {
      asm volatile("s_waitcnt vmcnt(4)" ::: "memory");
    } else {
      asm volatile("s_waitcnt vmcnt(0)" ::: "memory");
    }
    __builtin_amdgcn_s_barrier();
    __builtin_amdgcn_sched_barrier(0);
    __builtin_amdgcn_s_setprio(1);
    QUAD(avHi, bvHi, 4, 2);
    __builtin_amdgcn_s_setprio(0);
    __builtin_amdgcn_s_barrier();
  }
#undef QUAD
#undef RD
#undef STG_A
#undef STG_B

  // epilogue: + bias, -> bf16, qkv[b][t][o]
  unsigned short* outb = (unsigned short*)qkv + ((size_t)b * 8192 + t0) * 1536 + o0;
  float bias[4];
#pragma unroll
  for (int ni = 0; ni < 4; ni++) bias[ni] = bqkv[o0 + wn * 64 + ni * 16 + c];
#pragma unroll
  for (int mi = 0; mi < 8; mi++)
#pragma unroll
    for (int r = 0; r < 4; r++) {
      int t = wm * 128 + mi * 16 + g * 4 + r;
#pragma unroll
      for (int ni = 0; ni < 4; ni++) {
        int o = wn * 64 + ni * 16 + c;
        outb[(size_t)t * 1536 + o] = bf(acc[mi][ni][r] + bias[ni]);
      }
    }
}

// ---------------- kernel B: attention per (bg, h), 1 wave ----------------
__global__ __launch_bounds__(64) void k_attn(const __hip_bfloat16* __restrict__ qkv,
                                             const float* __restrict__ masks,
                                             __hip_bfloat16* __restrict__ a_out) {
  const int l = threadIdx.x, c = l & 15, g = l >> 4;
  const int h = blockIdx.x & 7, bg = blockIdx.x >> 3;
  const int gg = bg & 127, b = bg >> 7;
  const size_t rowstep = (size_t)128 * 1536;  // t += 128
  const __hip_bfloat16* base = qkv + ((size_t)b * 8192 + gg) * 1536 + h * 64;
  const __hip_bfloat16* Qb = base;
  const __hip_bfloat16* Kb = base + 512;
  const __hip_bfloat16* Vb = base + 1024;

  // load Q,K fragments (Q[i][d], K[j][d]; d k-contiguous)
  s16x8 kf[4][2], qf[4][2];
#pragma unroll
  for (int f = 0; f < 4; f++)
#pragma unroll
    for (int kk = 0; kk < 2; kk++) {
      size_t roff = (size_t)(f * 16 + c) * rowstep + kk * 32 + g * 8;
      kf[f][kk] = *(const s16x8*)(Kb + roff);
      qf[f][kk] = *(const s16x8*)(Qb + roff);
    }
  // S^T = K · Q^T : st[mj][ni], row=j, col=i
  f32x4 st[4][4];
#pragma unroll
  for (int i = 0; i < 4; i++)
#pragma unroll
    for (int j = 0; j < 4; j++) st[i][j] = (f32x4){0.f, 0.f, 0.f, 0.f};
#pragma unroll
  for (int mj = 0; mj < 4; mj++)
#pragma unroll
    for (int ni = 0; ni < 4; ni++)
#pragma unroll
      for (int kk = 0; kk < 2; kk++)
        st[mj][ni] = MFMA(kf[mj][kk], qf[ni][kk], st[mj][ni]);

  // key-side mask values for this lane's j rows
  float mk[4][4];
#pragma unroll
  for (int mj = 0; mj < 4; mj++)
#pragma unroll
    for (int r = 0; r < 4; r++)
      mk[mj][r] = masks[(size_t)b * 8192 + (size_t)(mj * 16 + g * 4 + r) * 128 + gg];

  // scale + mask + column softmax (over j)
  float inv[4];
#pragma unroll
  for (int ni = 0; ni < 4; ni++) {
    float m = -1e30f;
#pragma unroll
    for (int mj = 0; mj < 4; mj++)
#pragma unroll
      for (int r = 0; r < 4; r++) {
        float s = st[mj][ni][r] * 0.125f;
        s = (mk[mj][r] > 0.f) ? s : -1e9f;
        st[mj][ni][r] = s;
        m = fmaxf(m, s);
      }
    m = fmaxf(m, __shfl_xor(m, 16));
    m = fmaxf(m, __shfl_xor(m, 32));
    float sm = 0.f;
#pragma unroll
    for (int mj = 0; mj < 4; mj++)
#pragma unroll
      for (int r = 0; r < 4; r++) {
        float p = expf(st[mj][ni][r] - m);
        st[mj][ni][r] = p;
        sm += p;
      }
    sm += __shfl_xor(sm, 16);
    sm += __shfl_xor(sm, 32);
    inv[ni] = 1.f / sm;
  }
#pragma unroll
  for (int mj = 0; mj < 4; mj++)
#pragma unroll
    for (int ni = 0; ni < 4; ni++)
#pragma unroll
      for (int r = 0; r < 4; r++) st[mj][ni][r] *= inv[ni];

  // pack P^T to bf16 dwords: qd[ni][mj][w] = {reg 2w, reg 2w+1}
  unsigned qd[4][4][2];
#pragma unroll
  for (int ni = 0; ni < 4; ni++)
#pragma unroll
    for (int mj = 0; mj < 4; mj++)
#pragma unroll
      for (int wv = 0; wv < 2; wv++)
        qd[ni][mj][wv] = (unsigned)bf(st[mj][ni][2 * wv]) |
                         ((unsigned)bf(st[mj][ni][2 * wv + 1]) << 16);

  // PV: O[i][dh] += P[i][j] V[j][dh]
  f32x4 oacc[4][4];
#pragma unroll
  for (int i = 0; i < 4; i++)
#pragma unroll
    for (int j = 0; j < 4; j++) oacc[i][j] = (f32x4){0.f, 0.f, 0.f, 0.f};

  const int srcA = c + 32 * (g & 1);
  const int srcB = srcA + 16;
  const bool hi = (g >= 2);
#pragma unroll
  for (int kk = 0; kk < 2; kk++) {
    s16x8 af[4];
#pragma unroll
    for (int ni = 0; ni < 4; ni++) {
      unsigned a0 = __shfl(qd[ni][2 * kk][0], srcA);
      unsigned b0 = __shfl(qd[ni][2 * kk + 1][0], srcA);
      unsigned a1 = __shfl(qd[ni][2 * kk][1], srcA);
      unsigned b1 = __shfl(qd[ni][2 * kk + 1][1], srcA);
      unsigned a2 = __shfl(qd[ni][2 * kk][0], srcB);
      unsigned b2 = __shfl(qd[ni][2 * kk + 1][0], srcB);
      unsigned a3 = __shfl(qd[ni][2 * kk][1], srcB);
      unsigned b3 = __shfl(qd[ni][2 * kk + 1][1], srcB);
      union { unsigned u[4]; s16x8 v; } uu;
      uu.u[0] = hi ? b0 : a0;
      uu.u[1] = hi ? b1 : a1;
      uu.u[2] = hi ? b2 : a2;
      uu.u[3] = hi ? b3 : a3;
      af[ni] = uu.v;
    }
    s16x8 bvv[4];
#pragma unroll
    for (int fd = 0; fd < 4; fd++) {
      s16x8 t;
#pragma unroll
      for (int e = 0; e < 8; e++)
        t[e] = *(const short*)(Vb + (size_t)(kk * 32 + g * 8 + e) * rowstep + fd * 16 + c);
      bvv[fd] = t;
    }
#pragma unroll
    for (int fi = 0; fi < 4; fi++)
#pragma unroll
      for (int fd = 0; fd < 4; fd++)
        oacc[fi][fd] = MFMA(af[fi], bvv[fd], oacc[fi][fd]);
  }

  // GELU + store a[b][t][dk]
  unsigned short* ob = (unsigned short*)a_out + ((size_t)b * 8192 + gg) * 512 + h * 64;
#pragma unroll
  for (int fi = 0; fi < 4; fi++)
#pragma unroll
    for (int fd = 0; fd < 4; fd++)
#pragma unroll
      for (int r = 0; r < 4; r++) {
        float x = oacc[fi][fd][r];
        float ge = 0.5f * x * (1.f + erff(x * 0.70710678118f));
        int i = fi * 16 + g * 4 + r;
        ob[(size_t)i * (128 * 512) + fd * 16 + c] = bf(ge);
      }
}

// ---------------- kernel C: y[b][od][t] = (wo·a^T + bo) * mask (f32) ----------------
// M=od (256/WG), N=t (128/WG), K=512. 8 waves (4m x 2n).
__global__ __launch_bounds__(512) void k_out(const __hip_bfloat16* __restrict__ wob,
                                             const __hip_bfloat16* __restrict__ a,
                                             const float* __restrict__ bo,
                                             const float* __restrict__ masks,
                                             float* __restrict__ y) {
  __shared__ char smem[256 * 128 + 128 * 128];
  char* As = smem;            // 256 rows(od) x 128B
  char* Bs = smem + 32768;    // 128 rows(t) x 128B
  const int b = blockIdx.z, t0 = blockIdx.x * 128, o0 = blockIdx.y * 256;
  const int tid = threadIdx.x, l = tid & 63, w = tid >> 6;
  const int c = l & 15, g = l >> 4;
  const int wm = w >> 1, wn = w & 1;
  const int lrow = l >> 3, lcol = (l & 7) * 16;

  f32x4 acc[4][4];
#pragma unroll
  for (int i = 0; i < 4; i++)
#pragma unroll
    for (int j = 0; j < 4; j++) acc[i][j] = (f32x4){0.f, 0.f, 0.f, 0.f};

  const char* wbase = (const char*)(wob + (size_t)o0 * 512);
  const char* abase = (const char*)(a + ((size_t)b * 8192 + t0) * 512);

  for (int ks = 0; ks < 8; ks++) {
    __syncthreads();
#pragma unroll
    for (int ii = 0; ii < 4; ii++) {
      int row = w * 32 + ii * 8 + lrow;
      int cb = lcol ^ ((row & 7) << 4);
      const char* gp = wbase + (size_t)row * 1024 + ks * 128 + cb;
      GLOAD_LDS(gp, As + (w * 32 + ii * 8) * 128);
    }
#pragma unroll
    for (int ii = 0; ii < 2; ii++) {
      int row = w * 16 + ii * 8 + lrow;
      int cb = lcol ^ ((row & 7) << 4);
      const char* gp = abase + (size_t)row * 1024 + ks * 128 + cb;
      GLOAD_LDS(gp, Bs + (w * 16 + ii * 8) * 128);
    }
    __syncthreads();
#pragma unroll
    for (int kk = 0; kk < 2; kk++) {
      s16x8 av[4], bv[4];
#pragma unroll
      for (int mi = 0; mi < 4; mi++) {
        int row = wm * 64 + mi * 16 + c;
        int cb = (kk * 64 + g * 16) ^ ((row & 7) << 4);
        av[mi] = *(const s16x8*)(As + row * 128 + cb);
      }
#pragma unroll
      for (int ni = 0; ni < 4; ni++) {
        int row = wn * 64 + ni * 16 + c;
        int cb = (kk * 64 + g * 16) ^ ((row & 7) << 4);
        bv[ni] = *(const s16x8*)(Bs + row * 128 + cb);
      }
#pragma unroll
      for (int mi = 0; mi < 4; mi++)
#pragma unroll
        for (int ni = 0; ni < 4; ni++)
          acc[mi][ni] = MFMA(av[mi], bv[ni], acc[mi][ni]);
    }
  }
  // epilogue
  int tcol[4];
  float mk[4];
#pragma unroll
  for (int ni = 0; ni < 4; ni++) {
    tcol[ni] = t0 + wn * 64 + ni * 16 + c;
    mk[ni] = masks[(size_t)b * 8192 + tcol[ni]];
  }
#pragma unroll
  for (int mi = 0; mi < 4; mi++)
#pragma unroll
    for (int r = 0; r < 4; r++) {
      int od = o0 + wm * 64 + mi * 16 + g * 4 + r;
      float bias = bo[od];
      float* yrow = y + ((size_t)b * 1024 + od) * 8192;
#pragma unroll
      for (int ni = 0; ni < 4; ni++)
        yrow[tcol[ni]] = (acc[mi][ni][r] + bias) * mk[ni];
    }
}

// ---------------- launch ----------------
extern "C" void kernel_launch(void* const* d_in, const int* in_sizes, int n_in,
                              void* d_out, int out_size, void* d_ws, size_t ws_size,
                              hipStream_t stream) {
  const float* qk = (const float*)d_in[0];
  const float* masks = (const float*)d_in[1];
  const float* wq = (const float*)d_in[2];
  const float* bq = (const float*)d_in[3];
  const float* wk = (const float*)d_in[4];
  const float* bk = (const float*)d_in[5];
  const float* wv = (const float*)d_in[6];
  const float* bv = (const float*)d_in[7];
  const float* wo = (const float*)d_in[8];
  const float* bo = (const float*)d_in[9];

  char* ws = (char*)d_ws;
  __hip_bfloat16* qkT = (__hip_bfloat16*)ws;                       // 128 MB, dead after k_qkv
  __hip_bfloat16* a = (__hip_bfloat16*)ws;                         // 64 MB, written after qkT dead
  __hip_bfloat16* wqkv = (__hip_bfloat16*)(ws + 134217728);        // 3 MB
  __hip_bfloat16* wob = (__hip_bfloat16*)(ws + 134217728 + 3145728);  // 1 MB
  float* bqkv = (float*)(ws + 134217728 + 3145728 + 1048576);      // 6 KB

  __hip_bfloat16* qkv = (__hip_bfloat16*)d_out;  // 192 MB scratch in d_out (f32 out = 256 MB)
  float* y = (float*)d_out;

  k_prep<<<dim3(512), dim3(256), 0, stream>>>(wq, wk, wv, bq, bk, bv, wo, wqkv, wob, bqkv);
  k_transpose<<<dim3(128, 16, 8), dim3(256), 0, stream>>>(qk, qkT);
  k_qkv<<<dim3(32, 6, 8), dim3(512), 0, stream>>>(qkT, wqkv, bqkv, qkv);
  k_attn<<<dim3(8192), dim3(64), 0, stream>>>(qkv, masks, a);
  k_out<<<dim3(64, 4, 8), dim3(512), 0, stream>>>(wob, a, bo, masks, y);
}